// Round 3
// baseline (260.019 us; speedup 1.0000x reference)
//
#include <hip/hip_runtime.h>
#include <hip/hip_fp16.h>

#define NB   4
#define CIN  256
#define CM   128
#define NPIX 4096
#define LOG2E 1.44269504088896340736f

typedef _Float16 half_t;
typedef _Float16 f16x8 __attribute__((ext_vector_type(8)));
typedef _Float16 f16x4 __attribute__((ext_vector_type(4)));
typedef float    f32x4 __attribute__((ext_vector_type(4)));

static __device__ __forceinline__ f16x8 load8h(const half_t* p) {
    return *reinterpret_cast<const f16x8*>(p);
}
// async global->LDS, 16B per lane; LDS dest is wave-uniform base + lane*16
static __device__ __forceinline__ void gload_lds16(const void* g, void* l) {
    __builtin_amdgcn_global_load_lds(
        (const __attribute__((address_space(1))) unsigned int*)g,
        (__attribute__((address_space(3))) unsigned int*)l, 16, 0, 0);
}

// ---------------------------------------------------------------------------
// K0: convert the four weight matrices f32 -> f16 (one-time, every launch).
// 4 matrices x 32768 elems; 128 blocks x 256 thr, 4 elems/thread via float4.
// ---------------------------------------------------------------------------
__global__ __launch_bounds__(256) void k_pre(
    const float* __restrict__ tw, const float* __restrict__ pw,
    const float* __restrict__ gw, const float* __restrict__ Ww,
    half_t* __restrict__ TWh, half_t* __restrict__ PWh,
    half_t* __restrict__ GWh, half_t* __restrict__ WWh)
{
    const int m  = blockIdx.x >> 5;                 // which matrix
    const int i4 = (blockIdx.x & 31) * 256 + threadIdx.x;  // float4 index
    const float* src = m == 0 ? tw : m == 1 ? pw : m == 2 ? gw : Ww;
    half_t*      dst = m == 0 ? TWh : m == 1 ? PWh : m == 2 ? GWh : WWh;
    float4 a = reinterpret_cast<const float4*>(src)[i4];
    f16x4 h = {(_Float16)a.x, (_Float16)a.y, (_Float16)a.z, (_Float16)a.w};
    *reinterpret_cast<f16x4*>(dst + (size_t)i4 * 4) = h;
}

// ---------------------------------------------------------------------------
// K1: projections. T[b][i][c], P[b][j][c] (c contiguous), G[b][c][j] (j contiguous)
// MFMA 16x16x32 f16 layout: A[m][k]: m=l&15, k=kg*32+(l>>4)*8+e ; B[k][n]: n=l&15
//                           D: col=l&15, row=(l>>4)*4+reg
// ---------------------------------------------------------------------------
__global__ __launch_bounds__(256) void k_proj(
    const float* __restrict__ x,
    const half_t* __restrict__ tw, const float* __restrict__ tb,
    const half_t* __restrict__ pw, const float* __restrict__ pb,
    const half_t* __restrict__ gw, const float* __restrict__ gb,
    half_t* __restrict__ T, half_t* __restrict__ P, half_t* __restrict__ G)
{
    __shared__ half_t xT[64][280];  // [pos][k], pad 280 (reads: 2-way = free)
    const int b  = blockIdx.x >> 6;
    const int p0 = (blockIdx.x & 63) << 6;
    const int tid = threadIdx.x;
    const int lane = tid & 63, wv = tid >> 6;
    const int r15 = lane & 15, g4 = lane >> 4;

    {   // stage x[b][k][p0..p0+63] -> xT[pos][k] fp16, coalesced across lanes
        const float* xb = x + (size_t)b * CIN * NPIX + p0;
        const int ii = tid & 63;
        const int k0 = tid >> 6;
        #pragma unroll 4
        for (int kk = 0; kk < 64; ++kk) {
            int k = kk * 4 + k0;
            xT[ii][k] = (half_t)xb[(size_t)k * NPIX + ii];
        }
    }
    __syncthreads();

    f16x8 afr[8];
    #pragma unroll
    for (int kg = 0; kg < 8; ++kg)
        afr[kg] = load8h(&xT[wv * 16 + r15][kg * 32 + g4 * 8]);

    #pragma unroll
    for (int p = 0; p < 2; ++p) {   // theta, phi -> [pos][c]
        const half_t* wp = p ? pw : tw;
        const float*  bp = p ? pb : tb;
        half_t* OUT     = p ? P  : T;
        for (int cs = 0; cs < 8; ++cs) {
            f32x4 acc = {0.f, 0.f, 0.f, 0.f};
            const int crow = cs * 16 + r15;
            const half_t* wr = wp + (size_t)crow * CIN;
            #pragma unroll
            for (int kg = 0; kg < 8; ++kg) {
                f16x8 bf = load8h(wr + kg * 32 + g4 * 8);
                acc = __builtin_amdgcn_mfma_f32_16x16x32_f16(afr[kg], bf, acc, 0, 0, 0);
            }
            const float bias = bp[crow];
            #pragma unroll
            for (int r = 0; r < 4; ++r) {
                int pos = p0 + wv * 16 + g4 * 4 + r;
                OUT[((size_t)b * NPIX + pos) * CM + crow] = (half_t)(acc[r] + bias);
            }
        }
    }

    for (int cs = 0; cs < 8; ++cs) {   // g -> [c][j]
        f32x4 acc = {0.f, 0.f, 0.f, 0.f};
        const int crow = cs * 16 + r15;
        const half_t* wr = gw + (size_t)crow * CIN;
        #pragma unroll
        for (int kg = 0; kg < 8; ++kg) {
            f16x8 af = load8h(wr + kg * 32 + g4 * 8);
            acc = __builtin_amdgcn_mfma_f32_16x16x32_f16(af, afr[kg], acc, 0, 0, 0);
        }
        #pragma unroll
        for (int r = 0; r < 4; ++r) {
            int c = cs * 16 + g4 * 4 + r;
            int j = p0 + wv * 16 + r15;
            G[((size_t)b * CM + c) * NPIX + j] = (half_t)(acc[r] + gb[c]);
        }
    }
}

// ---------------------------------------------------------------------------
// K2: column-softmax stats. 512 thr; wave w owns i in [w*512, w*512+512) ->
// disjoint T reads. m2[j] = max_i f*log2e, rd[j] = 1/sum_i exp2(f*log2e - m2)
// ---------------------------------------------------------------------------
__global__ __launch_bounds__(512) void k_stats(
    const half_t* __restrict__ T, const half_t* __restrict__ P,
    float* __restrict__ M2, float* __restrict__ RD)
{
    __shared__ float partm[8][64];
    __shared__ float parts[8][64];
    const int b  = blockIdx.x >> 6;
    const int j0 = (blockIdx.x & 63) << 6;
    const int tid = threadIdx.x;
    const int lane = tid & 63, w = tid >> 6;
    const int r15 = lane & 15, g4 = lane >> 4;

    f16x8 bfr[4][4];   // P frags for the block's 4 j-sub-tiles
    const half_t* Pbase = P + (size_t)b * NPIX * CM;
    #pragma unroll
    for (int js = 0; js < 4; ++js)
        #pragma unroll
        for (int kg = 0; kg < 4; ++kg)
            bfr[js][kg] = load8h(Pbase + (size_t)(j0 + js * 16 + r15) * CM + kg * 32 + g4 * 8);

    float m2[4] = {-1e30f, -1e30f, -1e30f, -1e30f};
    float ss[4] = {0.f, 0.f, 0.f, 0.f};
    const half_t* Tb = T + (size_t)b * NPIX * CM;

    for (int it = 0; it < 8; ++it) {
        const int ibase = w * 512 + it * 64;
        #pragma unroll
        for (int is = 0; is < 4; ++is) {
            f16x8 af[4];
            const half_t* Tr = Tb + (size_t)(ibase + is * 16 + r15) * CM;
            #pragma unroll
            for (int kg = 0; kg < 4; ++kg) af[kg] = load8h(Tr + kg * 32 + g4 * 8);
            #pragma unroll
            for (int js = 0; js < 4; ++js) {
                f32x4 acc = {0.f, 0.f, 0.f, 0.f};
                #pragma unroll
                for (int kg = 0; kg < 4; ++kg)
                    acc = __builtin_amdgcn_mfma_f32_16x16x32_f16(af[kg], bfr[js][kg], acc, 0, 0, 0);
                float v0 = acc[0] * LOG2E, v1 = acc[1] * LOG2E;
                float v2 = acc[2] * LOG2E, v3 = acc[3] * LOG2E;
                float fm = fmaxf(fmaxf(v0, v1), fmaxf(v2, v3));
                float nm = fmaxf(m2[js], fm);
                ss[js] = ss[js] * exp2f(m2[js] - nm)
                       + (exp2f(v0 - nm) + exp2f(v1 - nm) + exp2f(v2 - nm) + exp2f(v3 - nm));
                m2[js] = nm;
            }
        }
    }
    #pragma unroll
    for (int js = 0; js < 4; ++js) {
        #pragma unroll
        for (int off = 16; off < 64; off <<= 1) {   // merge g4 groups (same j)
            float om = __shfl_xor(m2[js], off);
            float os = __shfl_xor(ss[js], off);
            float nm = fmaxf(m2[js], om);
            ss[js] = ss[js] * exp2f(m2[js] - nm) + os * exp2f(om - nm);
            m2[js] = nm;
        }
        if (g4 == 0) { partm[w][js * 16 + r15] = m2[js]; parts[w][js * 16 + r15] = ss[js]; }
    }
    __syncthreads();
    if (tid < 64) {   // merge 8 wave partials
        float m = -1e30f, s = 0.f;
        #pragma unroll
        for (int w2 = 0; w2 < 8; ++w2) {
            float om = partm[w2][tid], os = parts[w2][tid];
            float nm = fmaxf(m, om);
            s = s * exp2f(m - nm) + os * exp2f(om - nm);
            m = nm;
        }
        M2[b * NPIX + j0 + tid] = m;
        RD[b * NPIX + j0 + tid] = 1.0f / s;
    }
}

// ---------------------------------------------------------------------------
// K3: y[i][c] partial = sum_{j in half} w[i][j] * G[c][j].  Grid 512:
// (b, i-tile 64, j-half). P/G both double-buffered via global_load_lds with
// inverse-swizzled source + XOR-swizzled reads (rule #21 / T2).
// ONE barrier per j-tile: wlds rows are same-wave-written/read (lgkmcnt only).
// ---------------------------------------------------------------------------
__global__ __launch_bounds__(256) void k_attn(
    const half_t* __restrict__ T, const half_t* __restrict__ P,
    const half_t* __restrict__ G,
    const float* __restrict__ M2, const float* __restrict__ RD,
    half_t* __restrict__ Y0, half_t* __restrict__ Y1)
{
    __shared__ half_t Pst[2][64 * 128];   // [j'][c], 256B rows, dbuf (32 KB)
    __shared__ half_t Gst[2][128 * 64];   // [c][j'], 128B rows, dbuf (32 KB)
    __shared__ half_t wlds[64][72];       // w-tile [i'][j'] (9 KB)

    const int blk = blockIdx.x;
    const int b  = blk >> 7;
    const int ih = (blk >> 1) & 63;
    const int wg = blk & 1;
    const int i0 = ih << 6;
    const int tid = threadIdx.x;
    const int lane = tid & 63, wv = tid >> 6;
    const int r15 = lane & 15, g4 = lane >> 4;

    const half_t* Pb = P + (size_t)b * NPIX * CM;
    const half_t* Gb = G + (size_t)b * CM * NPIX;
    const float*  M2b = M2 + b * NPIX;
    const float*  RDb = RD + b * NPIX;

    f16x8 a1[4];
    const half_t* Tb = T + ((size_t)b * NPIX + i0 + wv * 16 + r15) * CM;
    #pragma unroll
    for (int kg = 0; kg < 4; ++kg) a1[kg] = load8h(Tb + kg * 32 + g4 * 8);

    f32x4 yacc[8];
    #pragma unroll
    for (int cs = 0; cs < 8; ++cs) yacc[cs] = (f32x4){0.f, 0.f, 0.f, 0.f};

    auto stageP = [&](int buf, int jb) {
        #pragma unroll
        for (int q = 0; q < 4; ++q) {
            int lo  = (wv * 4 + q) * 1024 + lane * 16;   // linear LDS byte offset
            int row = lo >> 8;                            // j' (0..63)
            int cb  = lo & 255;                           // c-byte
            const char* src = (const char*)Pb + (size_t)(jb + row) * (CM * 2)
                            + (cb ^ ((row & 7) << 4));    // inverse-swizzled source
            gload_lds16(src, (char*)&Pst[buf][0] + (wv * 4 + q) * 1024);
        }
    };
    auto stageG = [&](int buf, int jb) {
        #pragma unroll
        for (int q = 0; q < 4; ++q) {
            int lo  = (wv * 4 + q) * 1024 + lane * 16;
            int row = lo >> 7;                            // c (0..127)
            int cb  = lo & 127;                           // j'-byte
            const char* src = (const char*)Gb + (size_t)row * (NPIX * 2) + (size_t)jb * 2
                            + (cb ^ ((row & 7) << 4));
            gload_lds16(src, (char*)&Gst[buf][0] + (wv * 4 + q) * 1024);
        }
    };

    stageP(0, (wg * 32) * 64);
    stageG(0, (wg * 32) * 64);
    for (int jt = 0; jt < 32; ++jt) {
        const int jb = (wg * 32 + jt) * 64;
        const int cur = jt & 1;
        __syncthreads();   // drains vmcnt: buf[cur] ready; prior-iter reads done
        if (jt < 31) { stageP(cur ^ 1, jb + 64); stageG(cur ^ 1, jb + 64); }

        // f-tile + softmax weights -> wlds (own-wave rows, no barrier needed)
        const int swz = (r15 & 7) << 4;
        #pragma unroll
        for (int js = 0; js < 4; ++js) {
            f32x4 acc = {0.f, 0.f, 0.f, 0.f};
            const int row = js * 16 + r15;
            #pragma unroll
            for (int kg = 0; kg < 4; ++kg) {
                const char* pa = (const char*)&Pst[cur][0] + row * 256 + ((kg * 64 + g4 * 16) ^ swz);
                f16x8 bf = *reinterpret_cast<const f16x8*>(pa);
                acc = __builtin_amdgcn_mfma_f32_16x16x32_f16(a1[kg], bf, acc, 0, 0, 0);
            }
            const int j = jb + js * 16 + r15;
            const float mj = M2b[j], rdj = RDb[j];
            #pragma unroll
            for (int r = 0; r < 4; ++r) {
                float wgt = exp2f(fmaf(acc[r], LOG2E, -mj)) * rdj;
                wlds[wv * 16 + g4 * 4 + r][js * 16 + r15] = (half_t)wgt;
            }
        }

        // PV: D[i][c] += w[i][j] * G[c][j]
        f16x8 a2[2];
        #pragma unroll
        for (int kk = 0; kk < 2; ++kk)
            a2[kk] = load8h(&wlds[wv * 16 + r15][kk * 32 + g4 * 8]);
        #pragma unroll
        for (int cs = 0; cs < 8; ++cs) {
            const char* gbase = (const char*)&Gst[cur][0] + (cs * 16 + r15) * 128;
            #pragma unroll
            for (int kk = 0; kk < 2; ++kk) {
                f16x8 b2 = *reinterpret_cast<const f16x8*>(gbase + ((kk * 64 + g4 * 16) ^ swz));
                yacc[cs] = __builtin_amdgcn_mfma_f32_16x16x32_f16(a2[kk], b2, yacc[cs], 0, 0, 0);
            }
        }
    }

    half_t* Yp = wg ? Y1 : Y0;
    #pragma unroll
    for (int cs = 0; cs < 8; ++cs)
        #pragma unroll
        for (int r = 0; r < 4; ++r)
            Yp[((size_t)b * NPIX + i0 + wv * 16 + g4 * 4 + r) * CM + cs * 16 + r15]
                = (half_t)yacc[cs][r];
}

// ---------------------------------------------------------------------------
// K4: out[b][o][i] = x + W_b[o] + sum_c W_w[o][c] * (Y0+Y1)[i][c]
// ---------------------------------------------------------------------------
__global__ __launch_bounds__(256) void k_out(
    const half_t* __restrict__ Y0, const half_t* __restrict__ Y1,
    const half_t* __restrict__ Ww, const float* __restrict__ Wb,
    const float* __restrict__ x, float* __restrict__ out)
{
    const int b  = blockIdx.x >> 6;
    const int i0 = (blockIdx.x & 63) << 6;
    const int lane = threadIdx.x & 63, wv = threadIdx.x >> 6;
    const int r15 = lane & 15, g4 = lane >> 4;

    f16x8 yf[4];
    const size_t yrow = ((size_t)b * NPIX + i0 + wv * 16 + r15) * CM;
    #pragma unroll
    for (int kg = 0; kg < 4; ++kg) {
        f16x8 y0 = load8h(Y0 + yrow + kg * 32 + g4 * 8);
        f16x8 y1 = load8h(Y1 + yrow + kg * 32 + g4 * 8);
        yf[kg] = y0 + y1;
    }

    for (int os = 0; os < 16; ++os) {
        f32x4 acc = {0.f, 0.f, 0.f, 0.f};
        const half_t* wr = Ww + (size_t)(os * 16 + r15) * CM;
        #pragma unroll
        for (int kg = 0; kg < 4; ++kg) {
            f16x8 af = load8h(wr + kg * 32 + g4 * 8);
            acc = __builtin_amdgcn_mfma_f32_16x16x32_f16(af, yf[kg], acc, 0, 0, 0);
        }
        #pragma unroll
        for (int r = 0; r < 4; ++r) {
            int o = os * 16 + g4 * 4 + r;
            size_t addr = ((size_t)(b * CIN + o)) * NPIX + i0 + wv * 16 + r15;
            out[addr] = acc[r] + Wb[o] + x[addr];
        }
    }
}

extern "C" void kernel_launch(void* const* d_in, const int* in_sizes, int n_in,
                              void* d_out, int out_size, void* d_ws, size_t ws_size,
                              hipStream_t stream) {
    const float* x  = (const float*)d_in[0];
    const float* tw = (const float*)d_in[1];
    const float* tb = (const float*)d_in[2];
    const float* pw = (const float*)d_in[3];
    const float* pb = (const float*)d_in[4];
    const float* gw = (const float*)d_in[5];
    const float* gb = (const float*)d_in[6];
    const float* Ww = (const float*)d_in[7];
    const float* Wb = (const float*)d_in[8];
    float* out = (float*)d_out;

    const size_t SZ = (size_t)NB * NPIX * CM;   // 2M elements
    const size_t WSZ = (size_t)CM * CIN;        // 32768
    half_t* T   = (half_t*)d_ws;                // 4 MB
    half_t* P   = T + SZ;                       // 4 MB
    half_t* G   = P + SZ;                       // 4 MB
    half_t* Y0  = G + SZ;                       // 4 MB (f16 partial)
    half_t* Y1  = Y0 + SZ;                      // 4 MB
    half_t* TWh = Y1 + SZ;                      // 64 KB
    half_t* PWh = TWh + WSZ;
    half_t* GWh = PWh + WSZ;
    half_t* WWh = GWh + WSZ;
    float*  M2  = (float*)(WWh + WSZ);
    float*  RD  = M2 + (size_t)NB * NPIX;       // total ~20.4 MB

    hipLaunchKernelGGL(k_pre,   dim3(128), dim3(256), 0, stream,
                       tw, pw, gw, Ww, TWh, PWh, GWh, WWh);
    hipLaunchKernelGGL(k_proj,  dim3(256), dim3(256), 0, stream,
                       x, TWh, tb, PWh, pb, GWh, gb, T, P, G);
    hipLaunchKernelGGL(k_stats, dim3(256), dim3(512), 0, stream, T, P, M2, RD);
    hipLaunchKernelGGL(k_attn,  dim3(512), dim3(256), 0, stream,
                       T, P, G, M2, RD, Y0, Y1);
    hipLaunchKernelGGL(k_out,   dim3(256), dim3(256), 0, stream,
                       Y0, Y1, WWh, Wb, x, out);
}